// Round 1
// baseline (506.114 us; speedup 1.0000x reference)
//
#include <hip/hip_runtime.h>

#define NB 128
#define T_DIM 50
#define Q_DIM 1024
#define H_DIM 256
#define S_DIM 49                 // MAX_STEP - 1
#define K_DIM 51200              // T*Q
#define BK 64                    // K per LDS stage
#define GRAM_N (NB * NB)         // 16384
#define LROWU 36                 // uints per padded LDS row (64 f16 + 8 pad)
#define CPAD 132                 // padded f32 row for sinkhorn cost matrix

typedef __attribute__((ext_vector_type(4))) float f32x4;
typedef __attribute__((ext_vector_type(8))) _Float16 half8v;
typedef __attribute__((ext_vector_type(4))) unsigned int uint4v;
typedef __attribute__((ext_vector_type(2))) unsigned int uint2v;
using pk2_t = decltype(__builtin_amdgcn_cvt_pkrtz(0.0f, 0.0f));

union PKU { pk2_t p; unsigned int u; };
union U4H8 { uint4v u; half8v h; };

__device__ inline unsigned short f2bf_rn(float x) {   // round-nearest-even bf16
  union { float f; unsigned int u; } v; v.f = x;
  unsigned int r = v.u + 0x7FFFu + ((v.u >> 16) & 1u);
  return (unsigned short)(r >> 16);
}
__device__ inline float bf2f(unsigned short b) {
  union { float f; unsigned int u; } v; v.u = ((unsigned int)b) << 16;
  return v.f;
}

// ---------------------------------------------------------------------------
// Kernel 1: FUSED per-pair grams (XY, XX, YY) via 16x16x32 f16 MFMA.
// grid = (kchunks, 3 pairs), block = 1024 (16 waves).
// Round-5 restructure:
//   - kchunks doubled to 160 (kc=320, nstage=5) when ws permits -> 480 blocks
//     -> 2 blocks/CU co-resident (VGPR<=64 via __launch_bounds__(1024,8),
//     LDS 72KB x 2 = 144KB <= 160KB). A second resident block overlaps the
//     barrier/latency stalls that left MfmaUtil at 8%.
//   - Double-buffered LDS panels: ONE barrier per stage instead of two.
//     Safety: iter st = {write buf[st&1]; barrier; issue loads; compute
//     buf[st&1]}. The iter-(st-1) barrier orders iter-st writes after all
//     iter-(st-2) reads of the same buffer.
// ---------------------------------------------------------------------------
__global__ __launch_bounds__(1024, 8) void gram_fused_kernel(
    const float* __restrict__ s0, const float* __restrict__ s1, const float* __restrict__ s2,
    const float* __restrict__ t0, const float* __restrict__ t1, const float* __restrict__ t2,
    unsigned short* __restrict__ part, int kc, int nstage) {
  __shared__ unsigned int pan[2][2][NB * LROWU];   // [buf][A/B][...] 73728 B

  const int chunk = blockIdx.x;
  const int pair = blockIdx.y;
  const int kchunks = gridDim.x;
  const float* S  = (pair == 0) ? s0 : ((pair == 1) ? s1 : s2);
  const float* Tm = (pair == 0) ? t0 : ((pair == 1) ? t1 : t2);

  const int tid = threadIdx.x;
  const int wave = tid >> 6, lane = tid & 63;
  const int wrow = wave >> 2, wcol = wave & 3;
  const int l15 = lane & 15, quad = lane >> 4;

  f32x4 aXY[2][2], aXX[2][2], aYY[2][2];
#pragma unroll
  for (int i = 0; i < 2; i++)
#pragma unroll
    for (int j = 0; j < 2; j++) {
      aXY[i][j] = (f32x4){0.f, 0.f, 0.f, 0.f};
      aXX[i][j] = (f32x4){0.f, 0.f, 0.f, 0.f};
      aYY[i][j] = (f32x4){0.f, 0.f, 0.f, 0.f};
    }

  const int r0 = tid >> 4;              // 0..63 (i=0); i=1 -> r0+64
  const int kq = tid & 15;
  const size_t ro0 = (size_t)r0 * K_DIM;
  const size_t ro1 = (size_t)(r0 + 64) * K_DIM;

  const int kbase = chunk * kc;
  f32x4 pre0, pre1, pre2, pre3;

#define ISSUE_LOADS(KPOS)                                    \
  {                                                          \
    const float* pS = S + (KPOS) + kq * 4;                   \
    const float* pT = Tm + (KPOS) + kq * 4;                  \
    pre0 = *(const f32x4*)(pS + ro0);                        \
    pre1 = *(const f32x4*)(pS + ro1);                        \
    pre2 = *(const f32x4*)(pT + ro0);                        \
    pre3 = *(const f32x4*)(pT + ro1);                        \
  }

  ISSUE_LOADS(kbase)

  for (int st = 0; st < nstage; st++) {
    unsigned int* __restrict__ panA = &pan[st & 1][0][0];
    unsigned int* __restrict__ panB = &pan[st & 1][1][0];
    {                                   // cvt + LDS write (panel st)
      PKU a, b; uint2v w;
      a.p = __builtin_amdgcn_cvt_pkrtz(pre0[0], pre0[1]);
      b.p = __builtin_amdgcn_cvt_pkrtz(pre0[2], pre0[3]);
      w.x = a.u; w.y = b.u;
      *(uint2v*)&panA[r0 * LROWU + kq * 2] = w;
      a.p = __builtin_amdgcn_cvt_pkrtz(pre1[0], pre1[1]);
      b.p = __builtin_amdgcn_cvt_pkrtz(pre1[2], pre1[3]);
      w.x = a.u; w.y = b.u;
      *(uint2v*)&panA[(r0 + 64) * LROWU + kq * 2] = w;
      a.p = __builtin_amdgcn_cvt_pkrtz(pre2[0], pre2[1]);
      b.p = __builtin_amdgcn_cvt_pkrtz(pre2[2], pre2[3]);
      w.x = a.u; w.y = b.u;
      *(uint2v*)&panB[r0 * LROWU + kq * 2] = w;
      a.p = __builtin_amdgcn_cvt_pkrtz(pre3[0], pre3[1]);
      b.p = __builtin_amdgcn_cvt_pkrtz(pre3[2], pre3[3]);
      w.x = a.u; w.y = b.u;
      *(uint2v*)&panB[(r0 + 64) * LROWU + kq * 2] = w;
    }
    __syncthreads();                    // writes visible; also orders next
                                        // iter's writes after this buf's
                                        // prior-stage readers
    if (st + 1 < nstage) ISSUE_LOADS(kbase + (st + 1) * BK)

#pragma unroll
    for (int ks = 0; ks < 2; ks++) {
      const int kcc = ks * 16 + quad * 4;
      half8v as_[2], bs_[2], at_[2], bt_[2];
#pragma unroll
      for (int t = 0; t < 2; t++) {
        U4H8 u;
        u.u = *(const uint4v*)&panA[(wrow * 32 + t * 16 + l15) * LROWU + kcc]; as_[t] = u.h;
        u.u = *(const uint4v*)&panA[(wcol * 32 + t * 16 + l15) * LROWU + kcc]; bs_[t] = u.h;
        u.u = *(const uint4v*)&panB[(wrow * 32 + t * 16 + l15) * LROWU + kcc]; at_[t] = u.h;
        u.u = *(const uint4v*)&panB[(wcol * 32 + t * 16 + l15) * LROWU + kcc]; bt_[t] = u.h;
      }
#pragma unroll
      for (int ti = 0; ti < 2; ti++)
#pragma unroll
        for (int tj = 0; tj < 2; tj++) {
          aXY[ti][tj] = __builtin_amdgcn_mfma_f32_16x16x32_f16(as_[ti], bt_[tj], aXY[ti][tj], 0, 0, 0);
          aXX[ti][tj] = __builtin_amdgcn_mfma_f32_16x16x32_f16(as_[ti], bs_[tj], aXX[ti][tj], 0, 0, 0);
          aYY[ti][tj] = __builtin_amdgcn_mfma_f32_16x16x32_f16(at_[ti], bt_[tj], aYY[ti][tj], 0, 0, 0);
        }
    }
  }
#undef ISSUE_LOADS

#pragma unroll
  for (int kind = 0; kind < 3; kind++) {
    unsigned short* out = part + ((size_t)(pair * 3 + kind) * kchunks + chunk) * GRAM_N;
#pragma unroll
    for (int ti = 0; ti < 2; ti++)
#pragma unroll
      for (int tj = 0; tj < 2; tj++) {
        const f32x4 v = (kind == 0) ? aXY[ti][tj] : ((kind == 1) ? aXX[ti][tj] : aYY[ti][tj]);
        const int col = wcol * 32 + tj * 16 + l15;
#pragma unroll
        for (int r = 0; r < 4; r++) {
          const int row = wrow * 32 + ti * 16 + quad * 4 + r;
          out[(size_t)row * NB + col] = f2bf_rn(v[r]);
        }
      }
  }
}

// ---------------------------------------------------------------------------
// Kernel 2: reduce bf16 K-chunk partials -> gram[9][128][128] (f32)
// ---------------------------------------------------------------------------
__global__ __launch_bounds__(256) void gram_reduce_kernel(
    const unsigned short* __restrict__ part, float* __restrict__ gram, int kchunks) {
  const int idx = blockIdx.x * 256 + threadIdx.x;   // < 9*16384
  const int g = idx >> 14;
  const int cell = idx & (GRAM_N - 1);
  const unsigned short* p = part + (size_t)g * kchunks * GRAM_N + cell;
  float s = 0.f;
  for (int c = 0; c < kchunks; c++) s += bf2f(p[(size_t)c * GRAM_N]);
  gram[idx] = s;
}

// ---------------------------------------------------------------------------
// Kernel 3: Sinkhorn, per (pair, kind) chain. kind0: ft||gt; kind1: faa;
// kind2: gbb.
//  - C register-cached per thread (32 x f32x4, f32 exact).
//  - Two-pass softmin: pass1 max (fmax chain), pass2 sum of exp2.
//  - SAFETY (round-4 fix): exponent computed as (u - m) * k, subtract FIRST.
//    Float subtraction is monotone so u<=m => (u-m)<=0 => exp2<=1; the fma
//    form u*k - round(m*k) had rounding residual up to ~1e3 POSITIVE at
//    k~5.8e4 -> exp2(+1e3) = inf (round-4 failure).
// ---------------------------------------------------------------------------
__global__ __launch_bounds__(256, 1) void sinkhorn_part_kernel(
    const float* __restrict__ gram, float* __restrict__ kdpart) {
  const int pair = blockIdx.x, kind = blockIdx.y;
  const float* Gxy = gram + (size_t)(3 * pair + 0) * GRAM_N;
  const float* Gxx = gram + (size_t)(3 * pair + 1) * GRAM_N;
  const float* Gyy = gram + (size_t)(3 * pair + 2) * GRAM_N;

  __shared__ float CL[NB * CPAD];     // 67584 B, f32 cost matrix
  __shared__ f32x4 h4a[NB / 4];       // pot0 (f-side)
  __shared__ f32x4 h4b[NB / 4];       // pot1 (g-side, kind0 only)
  __shared__ float nx[NB], ny[NB];
  __shared__ float red[256];

  const int tid = threadIdx.x;
  if (tid < NB) {
    nx[tid] = Gxx[tid * (NB + 1)];
    ny[tid] = Gyy[tid * (NB + 1)];
    ((float*)h4a)[tid] = 0.f;
    ((float*)h4b)[tid] = 0.f;
  }
  __syncthreads();

  const float* G  = (kind == 0) ? Gxy : ((kind == 1) ? Gxx : Gyy);
  const float* rn = (kind == 2) ? ny : nx;
  const float* cn = (kind == 1) ? nx : ny;
  for (int idx = tid; idx < GRAM_N; idx += 256) {
    const int i = idx >> 7, j = idx & 127;
    CL[i * CPAD + j] = 2.0f * fmaxf(rn[i] + cn[j] - 2.0f * G[idx], 0.0f);
  }
  __syncthreads();

  const float rho = 250000.0f;
  const float AL = -4.852030263919617f;     // -log(128)
  const float LOG2E = 1.4426950408889634f;
  const float LN2 = 0.6931471805599453f;
  const int grp = tid >> 7;
  const int i = tid & 127;
  const bool active = (kind == 0) || (grp == 0);
  const bool colread = (kind == 0) && (grp == 1);

  // register-cache this thread's C row (or column for gt)
  f32x4 crow[32];
  if (active) {
    if (colread) {
#pragma unroll
      for (int jj = 0; jj < 32; jj++) {
        f32x4 v;
        v[0] = CL[(4 * jj + 0) * CPAD + i];
        v[1] = CL[(4 * jj + 1) * CPAD + i];
        v[2] = CL[(4 * jj + 2) * CPAD + i];
        v[3] = CL[(4 * jj + 3) * CPAD + i];
        crow[jj] = v;
      }
    } else {
#pragma unroll
      for (int jj = 0; jj < 32; jj++)
        crow[jj] = *(const f32x4*)&CL[i * CPAD + 4 * jj];
    }
  }

  float eps = 1.0f;
  for (int it = 0; it < 9; it++) {
    if (it == 8) eps = 2.5e-5f;             // BLUR^P
    const float inv_eps = 1.0f / eps;
    const float damp = 1.0f / (1.0f + eps / rho);
    const float ebl = eps * AL;

    float newp = 0.f;
    if (active) {
      const f32x4* h = (kind == 0 && grp == 0) ? h4b : h4a;
      // pass 1: m = max_j (h[j] - C[j])
      f32x4 m4 = (f32x4){-3.0e38f, -3.0e38f, -3.0e38f, -3.0e38f};
#pragma unroll
      for (int jj = 0; jj < 32; jj++) {
        const f32x4 u = h[jj] - crow[jj];
        m4[0] = fmaxf(m4[0], u[0]); m4[1] = fmaxf(m4[1], u[1]);
        m4[2] = fmaxf(m4[2], u[2]); m4[3] = fmaxf(m4[3], u[3]);
      }
      const float m = fmaxf(fmaxf(m4[0], m4[1]), fmaxf(m4[2], m4[3]));
      // pass 2: S = sum_j exp2((u - m) * k); subtract-first keeps arg <= 0
      const float k = inv_eps * LOG2E;
      f32x4 s4 = (f32x4){0.f, 0.f, 0.f, 0.f};
#pragma unroll
      for (int jj = 0; jj < 32; jj++) {
        const f32x4 u = h[jj] - crow[jj];
        s4[0] += __builtin_exp2f((u[0] - m) * k);
        s4[1] += __builtin_exp2f((u[1] - m) * k);
        s4[2] += __builtin_exp2f((u[2] - m) * k);
        s4[3] += __builtin_exp2f((u[3] - m) * k);
      }
      const float Ssum = (s4[0] + s4[1]) + (s4[2] + s4[3]);   // >= 1
      // softmin = -(m + ebl + eps*ln(S))
      const float sm = -(m + ebl + eps * (LN2 * __log2f(Ssum)));
      if (kind == 0) newp = damp * sm;
      else           newp = 0.5f * (((const float*)h4a)[i] + damp * sm);
    }
    __syncthreads();                        // all reads of h done
    if (active) {
      if (grp == 0) ((float*)h4a)[i] = newp;
      else          ((float*)h4b)[i] = newp;
    }
    __syncthreads();                        // new pots visible
    eps *= 0.25f;                           // SCALING^P
  }

  float v = 0.f;
  if (kind == 0) {
    v = (grp == 0) ? -__expf(-((const float*)h4a)[i] / rho)
                   : -__expf(-((const float*)h4b)[i] / rho);
  } else if (grp == 0) {
    v = __expf(-((const float*)h4a)[i] / rho);
  }
  red[tid] = v;
  __syncthreads();
  for (int st = 128; st > 0; st >>= 1) {
    if (tid < st) red[tid] += red[tid + st];
    __syncthreads();
  }
  if (tid == 0) kdpart[pair * 3 + kind] = red[0];
}

// ---------------------------------------------------------------------------
// Kernel 4: one-hot structure of delta -> gathers. block per (b,s).
// ---------------------------------------------------------------------------
__global__ __launch_bounds__(256) void ps_kernel(
    const float* __restrict__ lc, const float* __restrict__ lt, const float* __restrict__ le,
    const float* __restrict__ batch,
    float* __restrict__ pc, float* __restrict__ pt, float* __restrict__ pe,
    float* __restrict__ aarr) {
  const int bs = blockIdx.x;
  const int b = bs / S_DIM, s = bs % S_DIM;
  const float* brow = batch + ((size_t)b * T_DIM + (s + 1)) * (2 * Q_DIM);
  __shared__ int sq;
  __shared__ float sds;
  if (threadIdx.x == 0) sq = 0;
  __syncthreads();
  for (int q = threadIdx.x; q < Q_DIM; q += 256) {
    float d0 = brow[q], d1 = brow[Q_DIM + q];
    if (d0 + d1 > 0.5f) { sq = q; sds = d0 - d1; }   // exactly one thread fires
  }
  __syncthreads();
  if (threadIdx.x == 0) {
    const size_t off = ((size_t)b * T_DIM + s) * Q_DIM + sq;
    pc[bs] = 2.0f * lc[off];   // 1/TEMP
    pt[bs] = 2.0f * lt[off];
    pe[bs] = 2.0f * le[off];
    aarr[bs] = (sds > 0.0f) ? 1.0f : 0.0f;
  }
}

// ---------------------------------------------------------------------------
// Kernel 5: embed loss: sum of squared diffs.
// ---------------------------------------------------------------------------
__global__ __launch_bounds__(256) void embed_kernel(
    const f32x4* __restrict__ hs, const f32x4* __restrict__ ht,
    const f32x4* __restrict__ ds, const f32x4* __restrict__ dt,
    float* __restrict__ acc) {
  const int N4 = NB * T_DIM * H_DIM / 4;   // 409600
  float sum = 0.f;
  for (int idx = blockIdx.x * 256 + threadIdx.x; idx < N4; idx += gridDim.x * 256) {
    f32x4 a = hs[idx] - ht[idx];
    f32x4 b = ds[idx] - dt[idx];
    sum += a[0]*a[0] + a[1]*a[1] + a[2]*a[2] + a[3]*a[3]
         + b[0]*b[0] + b[1]*b[1] + b[2]*b[2] + b[3]*b[3];
  }
  for (int off = 32; off > 0; off >>= 1) sum += __shfl_down(sum, off, 64);
  __shared__ float wsum[4];
  const int lane = threadIdx.x & 63, wv = threadIdx.x >> 6;
  if (lane == 0) wsum[wv] = sum;
  __syncthreads();
  if (threadIdx.x == 0) atomicAdd(acc, wsum[0] + wsum[1] + wsum[2] + wsum[3]);
}

// ---------------------------------------------------------------------------
// Kernel 6: masked CE + final combine. 1 block, 128 threads.
// ---------------------------------------------------------------------------
__device__ inline float ce_row(const float* __restrict__ x, const float* __restrict__ a, int L) {
  float m = -3.0e38f;
  for (int s = 0; s < L; s++) m = fmaxf(m, x[s]);
  float sum = 0.f;
  for (int s = 0; s < L; s++) sum += __expf(x[s] - m);
  const float lse = m + __logf(sum);
  float loss = 0.f;
  for (int s = 0; s < L; s++) loss += a[s] * (x[s] - lse);
  return -loss;
}

__global__ __launch_bounds__(128) void ce_final_kernel(
    const float* __restrict__ pc, const float* __restrict__ pt, const float* __restrict__ pe,
    const float* __restrict__ aarr, const float* __restrict__ kdpart,
    const float* __restrict__ emb, float* __restrict__ out) {
  const int b = threadIdx.x;
  const float* xc = pc + b * S_DIM;
  const float* xt = pt + b * S_DIM;
  const float* xe = pe + b * S_DIM;
  const float* av = aarr + b * S_DIM;
  int last = -1;
  for (int s = 0; s < S_DIM; s++)
    if (xc[s] > 0.0f) last = s;
  const int L = (last >= 0) ? (last + 1) : S_DIM;
  float loss = ce_row(xt, av, L) + ce_row(xc, av, L) + ce_row(xe, av, L);
  __shared__ float red[128];
  red[b] = loss;
  __syncthreads();
  for (int st = 64; st > 0; st >>= 1) {
    if (b < st) red[b] += red[b + st];
    __syncthreads();
  }
  if (b == 0) {
    float kd = 0.f;
    for (int k = 0; k < 9; k++) kd += kdpart[k];
    // w * a_w = (rho + eps_final/2) / 128 ; DIST_W = 0.01
    out[0] = red[0] + 0.01f * (250000.0000125f / 128.0f) * kd + 0.5f * emb[0];
  }
}

// ---------------------------------------------------------------------------
extern "C" void kernel_launch(void* const* d_in, const int* in_sizes, int n_in,
                              void* d_out, int out_size, void* d_ws, size_t ws_size,
                              hipStream_t stream) {
  const float* lc    = (const float*)d_in[0];
  const float* lt    = (const float*)d_in[1];
  const float* le    = (const float*)d_in[2];
  const float* ltc   = (const float*)d_in[3];
  const float* ltt   = (const float*)d_in[4];
  const float* lte   = (const float*)d_in[5];
  const float* ohs   = (const float*)d_in[6];
  const float* oht   = (const float*)d_in[7];
  const float* ods   = (const float*)d_in[8];
  const float* odt   = (const float*)d_in[9];
  const float* batch = (const float*)d_in[10];

  // Pick kchunks=160 (2 blocks/CU) when workspace allows; fallback 80.
  int kchunks = 160, kc = 320, nstage = 5;
  {
    const size_t tail = ((size_t)9 * GRAM_N + 4 * NB * S_DIM + 9 + 1) * sizeof(float);
    size_t partBytes = (size_t)9 * kchunks * GRAM_N * sizeof(unsigned short);
    if (partBytes + tail > ws_size) { kchunks = 80; kc = 640; nstage = 10; }
  }

  unsigned short* part = (unsigned short*)d_ws;        // 9*kchunks*16384*2B
  float* gram = (float*)(part + (size_t)9 * kchunks * GRAM_N);  // 9*16384 f32
  float* pcb  = gram + 9 * GRAM_N;                     // 128*49 each
  float* ptb  = pcb + NB * S_DIM;
  float* peb  = ptb + NB * S_DIM;
  float* ab   = peb + NB * S_DIM;
  float* kdp  = ab + NB * S_DIM;                       // 9
  float* emb  = kdp + 9;                               // 1

  hipMemsetAsync(emb, 0, sizeof(float), stream);

  embed_kernel<<<512, 256, 0, stream>>>(
      (const f32x4*)ohs, (const f32x4*)oht, (const f32x4*)ods, (const f32x4*)odt, emb);

  ps_kernel<<<NB * S_DIM, 256, 0, stream>>>(lc, lt, le, batch, pcb, ptb, peb, ab);

  gram_fused_kernel<<<dim3(kchunks, 3), 1024, 0, stream>>>(lc, lt, le, ltc, ltt, lte, part, kc, nstage);

  gram_reduce_kernel<<<(9 * GRAM_N) / 256, 256, 0, stream>>>(part, gram, kchunks);

  sinkhorn_part_kernel<<<dim3(3, 3), 256, 0, stream>>>(gram, kdp);

  ce_final_kernel<<<1, 128, 0, stream>>>(pcb, ptb, peb, ab, kdp, emb, (float*)d_out);
}

// Round 2
// 412.940 us; speedup vs baseline: 1.2256x; 1.2256x over previous
//
#include <hip/hip_runtime.h>

#define NB 128
#define T_DIM 50
#define Q_DIM 1024
#define H_DIM 256
#define S_DIM 49                 // MAX_STEP - 1
#define K_DIM 51200              // T*Q
#define KCHUNKS 80
#define KC 640                   // K per block (chunk)
#define BK32 32                  // K per LDS stage
#define NST 20                   // KC/BK32
#define GRAM_N (NB * NB)         // 16384
#define LR 18                    // uints per padded LDS row (32 f16 + 4 pad)
#define CPAD 132                 // padded f32 row for sinkhorn cost matrix

typedef __attribute__((ext_vector_type(4))) float f32x4;
typedef __attribute__((ext_vector_type(8))) _Float16 half8v;
typedef __attribute__((ext_vector_type(4))) unsigned int uint4v;
typedef __attribute__((ext_vector_type(2))) unsigned int uint2v;
using pk2_t = decltype(__builtin_amdgcn_cvt_pkrtz(0.0f, 0.0f));

union PKU { pk2_t p; unsigned int u; };
union U4H8 { uint4v u; half8v h; };

__device__ inline unsigned short f2bf_rn(float x) {   // round-nearest-even bf16
  union { float f; unsigned int u; } v; v.f = x;
  unsigned int r = v.u + 0x7FFFu + ((v.u >> 16) & 1u);
  return (unsigned short)(r >> 16);
}
__device__ inline float bf2f(unsigned short b) {
  union { float f; unsigned int u; } v; v.u = ((unsigned int)b) << 16;
  return v.f;
}

// ---------------------------------------------------------------------------
// Kernel 1: UNFUSED per-(pair,kind) gram tiles via 16x16x32 f16 MFMA.
// grid = (9, KCHUNKS): x = pair*3+kind, y = K-chunk. block = 1024 (16 waves).
//
// Round-2 post-mortem: fusing XY/XX/YY in one block needs >=104 regs/lane
// (48 accum + 32 frag + 16 prefetch) -> forcing 2 blocks/CU via
// __launch_bounds__(1024,8) spilled accumulators (VGPR=32, WRITE_SIZE 363MB).
// Unfused blocks need only ~48 regs/lane (16 accum + 16 frag + 8 prefetch),
// which FITS the 64-reg budget of (1024,8) -> genuine 2 blocks/CU, and
// 720 blocks ≈ 2.8/CU so barrier stalls of one block overlap another's
// compute. Cost: S read by XY+XX blocks, T by XY+YY (2x logical reads), but
// all 157MB of unique input is L3-resident so HBM traffic is unchanged.
//
// Numerics identical to the verified round-0 kernel: same RTZ f32->f16 cvt,
// same MFMA, same 80x640 chunk split, same bf16 partials.
//
// Stage structure (BK=32, double-buffered, ONE barrier per stage):
//   iter st: [cvt+write buf st&1][issue loads st+1][sync][compute buf st&1]
// Hazard check: writes to buf (st+1)&1 in iter st+1 are ordered after all
// waves' compute of iter st-1 (same buffer) by the sync in iter st.
// ---------------------------------------------------------------------------
__global__ __launch_bounds__(1024, 8) void gram_unfused_kernel(
    const float* __restrict__ s0, const float* __restrict__ s1, const float* __restrict__ s2,
    const float* __restrict__ t0, const float* __restrict__ t1, const float* __restrict__ t2,
    unsigned short* __restrict__ part) {
  __shared__ unsigned int pan[2][2][NB * LR];   // [buf][A/B][128 rows x 18u] = 36864 B

  const int pk = blockIdx.x;                    // 0..8 = pair*3 + kind
  const int chunk = blockIdx.y;                 // 0..79
  const int pair = pk / 3;
  const int kind = pk - 3 * pair;               // 0: XY, 1: XX, 2: YY
  const float* Sp = (pair == 0) ? s0 : ((pair == 1) ? s1 : s2);
  const float* Tp = (pair == 0) ? t0 : ((pair == 1) ? t1 : t2);
  const float* P0 = (kind == 2) ? Tp : Sp;      // A-side panel source
  const float* P1 = Tp;                         // B-side panel source (XY only)
  const bool dual = (kind == 0);

  const int tid = threadIdx.x;
  const int wave = tid >> 6, lane = tid & 63;
  const int wrow = wave >> 2, wcol = wave & 3;
  const int l15 = lane & 15, quad = lane >> 4;

  f32x4 acc[2][2];
#pragma unroll
  for (int i = 0; i < 2; i++)
#pragma unroll
    for (int j = 0; j < 2; j++) acc[i][j] = (f32x4){0.f, 0.f, 0.f, 0.f};

  const int r0 = tid >> 3;              // 0..127 (staging row)
  const int kq = tid & 7;               // 0..7   (staging k-quad, 4 floats)
  const size_t ro = (size_t)r0 * K_DIM;
  const int kbase = chunk * KC;

  f32x4 pre0, pre1;
#define ISSUE(KP)                                                     \
  {                                                                   \
    pre0 = *(const f32x4*)(P0 + ro + (KP) + kq * 4);                  \
    if (dual) pre1 = *(const f32x4*)(P1 + ro + (KP) + kq * 4);        \
  }

  ISSUE(kbase)

  for (int st = 0; st < NST; st++) {
    const int buf = st & 1;
    {                                   // cvt + LDS write (stage st)
      PKU a, b; uint2v w;
      a.p = __builtin_amdgcn_cvt_pkrtz(pre0[0], pre0[1]);
      b.p = __builtin_amdgcn_cvt_pkrtz(pre0[2], pre0[3]);
      w.x = a.u; w.y = b.u;
      *(uint2v*)&pan[buf][0][r0 * LR + kq * 2] = w;
      if (dual) {
        a.p = __builtin_amdgcn_cvt_pkrtz(pre1[0], pre1[1]);
        b.p = __builtin_amdgcn_cvt_pkrtz(pre1[2], pre1[3]);
        w.x = a.u; w.y = b.u;
        *(uint2v*)&pan[buf][1][r0 * LR + kq * 2] = w;
      }
    }
    if (st + 1 < NST) ISSUE(kbase + (st + 1) * BK32)   // loads in flight across barrier
    __syncthreads();                    // stage-st panel visible

    const unsigned int* pa = &pan[buf][0][0];
    const unsigned int* pb = &pan[buf][dual ? 1 : 0][0];
    half8v af[2], bf[2];
#pragma unroll
    for (int t = 0; t < 2; t++) {
      U4H8 u;
      u.u = *(const uint4v*)&pa[(wrow * 32 + t * 16 + l15) * LR + quad * 4]; af[t] = u.h;
      u.u = *(const uint4v*)&pb[(wcol * 32 + t * 16 + l15) * LR + quad * 4]; bf[t] = u.h;
    }
#pragma unroll
    for (int ti = 0; ti < 2; ti++)
#pragma unroll
      for (int tj = 0; tj < 2; tj++)
        acc[ti][tj] = __builtin_amdgcn_mfma_f32_16x16x32_f16(af[ti], bf[tj], acc[ti][tj], 0, 0, 0);
  }
#undef ISSUE

  unsigned short* out = part + ((size_t)pk * KCHUNKS + chunk) * GRAM_N;
#pragma unroll
  for (int ti = 0; ti < 2; ti++)
#pragma unroll
    for (int tj = 0; tj < 2; tj++) {
      const int col = wcol * 32 + tj * 16 + l15;
#pragma unroll
      for (int r = 0; r < 4; r++) {
        const int row = wrow * 32 + ti * 16 + quad * 4 + r;
        out[(size_t)row * NB + col] = f2bf_rn(acc[ti][tj][r]);
      }
    }
}

// ---------------------------------------------------------------------------
// Kernel 2: reduce bf16 K-chunk partials -> gram[9][128][128] (f32)
// ---------------------------------------------------------------------------
__global__ __launch_bounds__(256) void gram_reduce_kernel(
    const unsigned short* __restrict__ part, float* __restrict__ gram) {
  const int idx = blockIdx.x * 256 + threadIdx.x;   // < 9*16384
  const int g = idx >> 14;
  const int cell = idx & (GRAM_N - 1);
  const unsigned short* p = part + (size_t)g * KCHUNKS * GRAM_N + cell;
  float s = 0.f;
#pragma unroll
  for (int c = 0; c < KCHUNKS; c++) s += bf2f(p[(size_t)c * GRAM_N]);
  gram[idx] = s;
}

// ---------------------------------------------------------------------------
// Kernel 3: Sinkhorn, per (pair, kind) chain. kind0: ft||gt; kind1: faa;
// kind2: gbb.
//  - C register-cached per thread (32 x f32x4, f32 exact).
//  - Two-pass softmin: pass1 max (fmax chain), pass2 sum of exp2.
//  - SAFETY: exponent computed as (u - m) * k, subtract FIRST (monotone).
// ---------------------------------------------------------------------------
__global__ __launch_bounds__(256, 1) void sinkhorn_part_kernel(
    const float* __restrict__ gram, float* __restrict__ kdpart) {
  const int pair = blockIdx.x, kind = blockIdx.y;
  const float* Gxy = gram + (size_t)(3 * pair + 0) * GRAM_N;
  const float* Gxx = gram + (size_t)(3 * pair + 1) * GRAM_N;
  const float* Gyy = gram + (size_t)(3 * pair + 2) * GRAM_N;

  __shared__ float CL[NB * CPAD];     // 67584 B, f32 cost matrix
  __shared__ f32x4 h4a[NB / 4];       // pot0 (f-side)
  __shared__ f32x4 h4b[NB / 4];       // pot1 (g-side, kind0 only)
  __shared__ float nx[NB], ny[NB];
  __shared__ float red[256];

  const int tid = threadIdx.x;
  if (tid < NB) {
    nx[tid] = Gxx[tid * (NB + 1)];
    ny[tid] = Gyy[tid * (NB + 1)];
    ((float*)h4a)[tid] = 0.f;
    ((float*)h4b)[tid] = 0.f;
  }
  __syncthreads();

  const float* G  = (kind == 0) ? Gxy : ((kind == 1) ? Gxx : Gyy);
  const float* rn = (kind == 2) ? ny : nx;
  const float* cn = (kind == 1) ? nx : ny;
  for (int idx = tid; idx < GRAM_N; idx += 256) {
    const int i = idx >> 7, j = idx & 127;
    CL[i * CPAD + j] = 2.0f * fmaxf(rn[i] + cn[j] - 2.0f * G[idx], 0.0f);
  }
  __syncthreads();

  const float rho = 250000.0f;
  const float AL = -4.852030263919617f;     // -log(128)
  const float LOG2E = 1.4426950408889634f;
  const float LN2 = 0.6931471805599453f;
  const int grp = tid >> 7;
  const int i = tid & 127;
  const bool active = (kind == 0) || (grp == 0);
  const bool colread = (kind == 0) && (grp == 1);

  // register-cache this thread's C row (or column for gt)
  f32x4 crow[32];
  if (active) {
    if (colread) {
#pragma unroll
      for (int jj = 0; jj < 32; jj++) {
        f32x4 v;
        v[0] = CL[(4 * jj + 0) * CPAD + i];
        v[1] = CL[(4 * jj + 1) * CPAD + i];
        v[2] = CL[(4 * jj + 2) * CPAD + i];
        v[3] = CL[(4 * jj + 3) * CPAD + i];
        crow[jj] = v;
      }
    } else {
#pragma unroll
      for (int jj = 0; jj < 32; jj++)
        crow[jj] = *(const f32x4*)&CL[i * CPAD + 4 * jj];
    }
  }

  float eps = 1.0f;
  for (int it = 0; it < 9; it++) {
    if (it == 8) eps = 2.5e-5f;             // BLUR^P
    const float inv_eps = 1.0f / eps;
    const float damp = 1.0f / (1.0f + eps / rho);
    const float ebl = eps * AL;

    float newp = 0.f;
    if (active) {
      const f32x4* h = (kind == 0 && grp == 0) ? h4b : h4a;
      // pass 1: m = max_j (h[j] - C[j])
      f32x4 m4 = (f32x4){-3.0e38f, -3.0e38f, -3.0e38f, -3.0e38f};
#pragma unroll
      for (int jj = 0; jj < 32; jj++) {
        const f32x4 u = h[jj] - crow[jj];
        m4[0] = fmaxf(m4[0], u[0]); m4[1] = fmaxf(m4[1], u[1]);
        m4[2] = fmaxf(m4[2], u[2]); m4[3] = fmaxf(m4[3], u[3]);
      }
      const float m = fmaxf(fmaxf(m4[0], m4[1]), fmaxf(m4[2], m4[3]));
      // pass 2: S = sum_j exp2((u - m) * k); subtract-first keeps arg <= 0
      const float k = inv_eps * LOG2E;
      f32x4 s4 = (f32x4){0.f, 0.f, 0.f, 0.f};
#pragma unroll
      for (int jj = 0; jj < 32; jj++) {
        const f32x4 u = h[jj] - crow[jj];
        s4[0] += __builtin_exp2f((u[0] - m) * k);
        s4[1] += __builtin_exp2f((u[1] - m) * k);
        s4[2] += __builtin_exp2f((u[2] - m) * k);
        s4[3] += __builtin_exp2f((u[3] - m) * k);
      }
      const float Ssum = (s4[0] + s4[1]) + (s4[2] + s4[3]);   // >= 1
      // softmin = -(m + ebl + eps*ln(S))
      const float sm = -(m + ebl + eps * (LN2 * __log2f(Ssum)));
      if (kind == 0) newp = damp * sm;
      else           newp = 0.5f * (((const float*)h4a)[i] + damp * sm);
    }
    __syncthreads();                        // all reads of h done
    if (active) {
      if (grp == 0) ((float*)h4a)[i] = newp;
      else          ((float*)h4b)[i] = newp;
    }
    __syncthreads();                        // new pots visible
    eps *= 0.25f;                           // SCALING^P
  }

  float v = 0.f;
  if (kind == 0) {
    v = (grp == 0) ? -__expf(-((const float*)h4a)[i] / rho)
                   : -__expf(-((const float*)h4b)[i] / rho);
  } else if (grp == 0) {
    v = __expf(-((const float*)h4a)[i] / rho);
  }
  red[tid] = v;
  __syncthreads();
  for (int st = 128; st > 0; st >>= 1) {
    if (tid < st) red[tid] += red[tid + st];
    __syncthreads();
  }
  if (tid == 0) kdpart[pair * 3 + kind] = red[0];
}

// ---------------------------------------------------------------------------
// Kernel 4: one-hot structure of delta -> gathers. block per (b,s).
// ---------------------------------------------------------------------------
__global__ __launch_bounds__(256) void ps_kernel(
    const float* __restrict__ lc, const float* __restrict__ lt, const float* __restrict__ le,
    const float* __restrict__ batch,
    float* __restrict__ pc, float* __restrict__ pt, float* __restrict__ pe,
    float* __restrict__ aarr) {
  const int bs = blockIdx.x;
  const int b = bs / S_DIM, s = bs % S_DIM;
  const float* brow = batch + ((size_t)b * T_DIM + (s + 1)) * (2 * Q_DIM);
  __shared__ int sq;
  __shared__ float sds;
  if (threadIdx.x == 0) sq = 0;
  __syncthreads();
  for (int q = threadIdx.x; q < Q_DIM; q += 256) {
    float d0 = brow[q], d1 = brow[Q_DIM + q];
    if (d0 + d1 > 0.5f) { sq = q; sds = d0 - d1; }   // exactly one thread fires
  }
  __syncthreads();
  if (threadIdx.x == 0) {
    const size_t off = ((size_t)b * T_DIM + s) * Q_DIM + sq;
    pc[bs] = 2.0f * lc[off];   // 1/TEMP
    pt[bs] = 2.0f * lt[off];
    pe[bs] = 2.0f * le[off];
    aarr[bs] = (sds > 0.0f) ? 1.0f : 0.0f;
  }
}

// ---------------------------------------------------------------------------
// Kernel 5: embed loss: sum of squared diffs.
// ---------------------------------------------------------------------------
__global__ __launch_bounds__(256) void embed_kernel(
    const f32x4* __restrict__ hs, const f32x4* __restrict__ ht,
    const f32x4* __restrict__ ds, const f32x4* __restrict__ dt,
    float* __restrict__ acc) {
  const int N4 = NB * T_DIM * H_DIM / 4;   // 409600
  float sum = 0.f;
  for (int idx = blockIdx.x * 256 + threadIdx.x; idx < N4; idx += gridDim.x * 256) {
    f32x4 a = hs[idx] - ht[idx];
    f32x4 b = ds[idx] - dt[idx];
    sum += a[0]*a[0] + a[1]*a[1] + a[2]*a[2] + a[3]*a[3]
         + b[0]*b[0] + b[1]*b[1] + b[2]*b[2] + b[3]*b[3];
  }
  for (int off = 32; off > 0; off >>= 1) sum += __shfl_down(sum, off, 64);
  __shared__ float wsum[4];
  const int lane = threadIdx.x & 63, wv = threadIdx.x >> 6;
  if (lane == 0) wsum[wv] = sum;
  __syncthreads();
  if (threadIdx.x == 0) atomicAdd(acc, wsum[0] + wsum[1] + wsum[2] + wsum[3]);
}

// ---------------------------------------------------------------------------
// Kernel 6: masked CE + final combine. 1 block, 128 threads.
// ---------------------------------------------------------------------------
__device__ inline float ce_row(const float* __restrict__ x, const float* __restrict__ a, int L) {
  float m = -3.0e38f;
  for (int s = 0; s < L; s++) m = fmaxf(m, x[s]);
  float sum = 0.f;
  for (int s = 0; s < L; s++) sum += __expf(x[s] - m);
  const float lse = m + __logf(sum);
  float loss = 0.f;
  for (int s = 0; s < L; s++) loss += a[s] * (x[s] - lse);
  return -loss;
}

__global__ __launch_bounds__(128) void ce_final_kernel(
    const float* __restrict__ pc, const float* __restrict__ pt, const float* __restrict__ pe,
    const float* __restrict__ aarr, const float* __restrict__ kdpart,
    const float* __restrict__ emb, float* __restrict__ out) {
  const int b = threadIdx.x;
  const float* xc = pc + b * S_DIM;
  const float* xt = pt + b * S_DIM;
  const float* xe = pe + b * S_DIM;
  const float* av = aarr + b * S_DIM;
  int last = -1;
  for (int s = 0; s < S_DIM; s++)
    if (xc[s] > 0.0f) last = s;
  const int L = (last >= 0) ? (last + 1) : S_DIM;
  float loss = ce_row(xt, av, L) + ce_row(xc, av, L) + ce_row(xe, av, L);
  __shared__ float red[128];
  red[b] = loss;
  __syncthreads();
  for (int st = 64; st > 0; st >>= 1) {
    if (b < st) red[b] += red[b + st];
    __syncthreads();
  }
  if (b == 0) {
    float kd = 0.f;
    for (int k = 0; k < 9; k++) kd += kdpart[k];
    // w * a_w = (rho + eps_final/2) / 128 ; DIST_W = 0.01
    out[0] = red[0] + 0.01f * (250000.0000125f / 128.0f) * kd + 0.5f * emb[0];
  }
}

// ---------------------------------------------------------------------------
extern "C" void kernel_launch(void* const* d_in, const int* in_sizes, int n_in,
                              void* d_out, int out_size, void* d_ws, size_t ws_size,
                              hipStream_t stream) {
  const float* lc    = (const float*)d_in[0];
  const float* lt    = (const float*)d_in[1];
  const float* le    = (const float*)d_in[2];
  const float* ltc   = (const float*)d_in[3];
  const float* ltt   = (const float*)d_in[4];
  const float* lte   = (const float*)d_in[5];
  const float* ohs   = (const float*)d_in[6];
  const float* oht   = (const float*)d_in[7];
  const float* ods   = (const float*)d_in[8];
  const float* odt   = (const float*)d_in[9];
  const float* batch = (const float*)d_in[10];

  unsigned short* part = (unsigned short*)d_ws;        // 9*80*16384*2B = 23.6 MB
  float* gram = (float*)(part + (size_t)9 * KCHUNKS * GRAM_N);  // 9*16384 f32
  float* pcb  = gram + 9 * GRAM_N;                     // 128*49 each
  float* ptb  = pcb + NB * S_DIM;
  float* peb  = ptb + NB * S_DIM;
  float* ab   = peb + NB * S_DIM;
  float* kdp  = ab + NB * S_DIM;                       // 9
  float* emb  = kdp + 9;                               // 1

  hipMemsetAsync(emb, 0, sizeof(float), stream);

  embed_kernel<<<512, 256, 0, stream>>>(
      (const f32x4*)ohs, (const f32x4*)oht, (const f32x4*)ods, (const f32x4*)odt, emb);

  ps_kernel<<<NB * S_DIM, 256, 0, stream>>>(lc, lt, le, batch, pcb, ptb, peb, ab);

  gram_unfused_kernel<<<dim3(9, KCHUNKS), 1024, 0, stream>>>(lc, lt, le, ltc, ltt, lte, part);

  gram_reduce_kernel<<<(9 * GRAM_N) / 256, 256, 0, stream>>>(part, gram);

  sinkhorn_part_kernel<<<dim3(3, 3), 256, 0, stream>>>(gram, kdp);

  ce_final_kernel<<<1, 128, 0, stream>>>(pcb, ptb, peb, ab, kdp, emb, (float*)d_out);
}

// Round 3
// 344.244 us; speedup vs baseline: 1.4702x; 1.1996x over previous
//
#include <hip/hip_runtime.h>

#define NB 128
#define T_DIM 50
#define Q_DIM 1024
#define H_DIM 256
#define S_DIM 49                 // MAX_STEP - 1
#define K_DIM 51200              // T*Q
#define KCHUNKS 80
#define KC 640                   // K per block
#define BK 64                    // K per LDS stage
#define NSTAGE 10                // KC/BK
#define GRAM_N (NB * NB)         // 16384
#define LROWU 36                 // uints per padded LDS row (64 f16 + 8 pad)
#define CPAD 132                 // padded f32 row for sinkhorn cost matrix

typedef __attribute__((ext_vector_type(4))) float f32x4;
typedef __attribute__((ext_vector_type(8))) _Float16 half8v;
typedef __attribute__((ext_vector_type(4))) unsigned int uint4v;
typedef __attribute__((ext_vector_type(2))) unsigned int uint2v;
using pk2_t = decltype(__builtin_amdgcn_cvt_pkrtz(0.0f, 0.0f));

union PKU { pk2_t p; unsigned int u; };
union U4H8 { uint4v u; half8v h; };

__device__ inline unsigned short f2bf_rn(float x) {   // round-nearest-even bf16
  union { float f; unsigned int u; } v; v.f = x;
  unsigned int r = v.u + 0x7FFFu + ((v.u >> 16) & 1u);
  return (unsigned short)(r >> 16);
}
__device__ inline float bf2f(unsigned short b) {
  union { float f; unsigned int u; } v; v.u = ((unsigned int)b) << 16;
  return v.f;
}

// ---------------------------------------------------------------------------
// Kernel 1: FUSED per-pair grams (XY, XX, YY) via 16x16x32 f16 MFMA.
// grid = (KCHUNKS, 3), block = 1024 (16 waves), 1 block/CU (by LDS+regs).
//
// Round-3 restructure (vs verified round-0): double-buffered LDS + ONE
// barrier per stage, with the stage body re-ordered so a FULL compute phase
// (~3000 cy of ds_read+MFMA) sits between load-issue and the vmcnt wait:
//   prologue: issue(0); cvt+write buf0; barrier
//   iter st : issue(st+1); compute buf[st&1]; cvt+write buf[(st+1)&1]; barrier
// Hazards: write(st+1) targets buffer (st+1)&1, last read by compute(st-1),
// separated by the barrier at end of iter st-1. compute(st+1) follows the
// barrier at end of iter st, seeing the writes. WAR on pre registers is safe:
// issue(st+1) overwrites pre only after cvt+write(st) consumed it (previous
// iteration). Numerics identical to round 0 (same RTZ cvt, MFMA, chunking).
// NO __launch_bounds__ min-waves: round-1 showed forcing 8 waves/EU spills
// accumulators (fused needs ~104 unified regs/lane).
// ---------------------------------------------------------------------------
__global__ __launch_bounds__(1024) void gram_fused_kernel(
    const float* __restrict__ s0, const float* __restrict__ s1, const float* __restrict__ s2,
    const float* __restrict__ t0, const float* __restrict__ t1, const float* __restrict__ t2,
    unsigned short* __restrict__ part) {
  __shared__ unsigned int pan[2][2][NB * LROWU];   // [buf][A/B], 73728 B

  const int chunk = blockIdx.x;
  const int pair = blockIdx.y;
  const float* S  = (pair == 0) ? s0 : ((pair == 1) ? s1 : s2);
  const float* Tm = (pair == 0) ? t0 : ((pair == 1) ? t1 : t2);

  const int tid = threadIdx.x;
  const int wave = tid >> 6, lane = tid & 63;
  const int wrow = wave >> 2, wcol = wave & 3;
  const int l15 = lane & 15, quad = lane >> 4;

  f32x4 aXY[2][2], aXX[2][2], aYY[2][2];
#pragma unroll
  for (int i = 0; i < 2; i++)
#pragma unroll
    for (int j = 0; j < 2; j++) {
      aXY[i][j] = (f32x4){0.f, 0.f, 0.f, 0.f};
      aXX[i][j] = (f32x4){0.f, 0.f, 0.f, 0.f};
      aYY[i][j] = (f32x4){0.f, 0.f, 0.f, 0.f};
    }

  const int r0 = tid >> 4;              // 0..63 (i=0); i=1 -> r0+64
  const int kq = tid & 15;
  const size_t ro0 = (size_t)r0 * K_DIM;
  const size_t ro1 = (size_t)(r0 + 64) * K_DIM;

  const int kbase = chunk * KC;
  f32x4 pre0, pre1, pre2, pre3;

#define ISSUE_LOADS(KPOS)                                    \
  {                                                          \
    const float* pS = S + (KPOS) + kq * 4;                   \
    const float* pT = Tm + (KPOS) + kq * 4;                  \
    pre0 = *(const f32x4*)(pS + ro0);                        \
    pre1 = *(const f32x4*)(pS + ro1);                        \
    pre2 = *(const f32x4*)(pT + ro0);                        \
    pre3 = *(const f32x4*)(pT + ro1);                        \
  }

#define CVT_WRITE(BUF)                                       \
  {                                                          \
    unsigned int* panA = &pan[BUF][0][0];                    \
    unsigned int* panB = &pan[BUF][1][0];                    \
    PKU a, b; uint2v w;                                      \
    a.p = __builtin_amdgcn_cvt_pkrtz(pre0[0], pre0[1]);      \
    b.p = __builtin_amdgcn_cvt_pkrtz(pre0[2], pre0[3]);      \
    w.x = a.u; w.y = b.u;                                    \
    *(uint2v*)&panA[r0 * LROWU + kq * 2] = w;                \
    a.p = __builtin_amdgcn_cvt_pkrtz(pre1[0], pre1[1]);      \
    b.p = __builtin_amdgcn_cvt_pkrtz(pre1[2], pre1[3]);      \
    w.x = a.u; w.y = b.u;                                    \
    *(uint2v*)&panA[(r0 + 64) * LROWU + kq * 2] = w;         \
    a.p = __builtin_amdgcn_cvt_pkrtz(pre2[0], pre2[1]);      \
    b.p = __builtin_amdgcn_cvt_pkrtz(pre2[2], pre2[3]);      \
    w.x = a.u; w.y = b.u;                                    \
    *(uint2v*)&panB[r0 * LROWU + kq * 2] = w;                \
    a.p = __builtin_amdgcn_cvt_pkrtz(pre3[0], pre3[1]);      \
    b.p = __builtin_amdgcn_cvt_pkrtz(pre3[2], pre3[3]);      \
    w.x = a.u; w.y = b.u;                                    \
    *(uint2v*)&panB[(r0 + 64) * LROWU + kq * 2] = w;         \
  }

  ISSUE_LOADS(kbase)
  CVT_WRITE(0)
  __syncthreads();

  for (int st = 0; st < NSTAGE; st++) {
    const int buf = st & 1;
    if (st + 1 < NSTAGE) ISSUE_LOADS(kbase + (st + 1) * BK)   // in flight across compute

    {                                  // compute stage st from pan[buf]
      const unsigned int* panA = &pan[buf][0][0];
      const unsigned int* panB = &pan[buf][1][0];
#pragma unroll
      for (int ks = 0; ks < 2; ks++) {
        const int kc = ks * 16 + quad * 4;
        half8v as_[2], bs_[2], at_[2], bt_[2];
#pragma unroll
        for (int t = 0; t < 2; t++) {
          U4H8 u;
          u.u = *(const uint4v*)&panA[(wrow * 32 + t * 16 + l15) * LROWU + kc]; as_[t] = u.h;
          u.u = *(const uint4v*)&panA[(wcol * 32 + t * 16 + l15) * LROWU + kc]; bs_[t] = u.h;
          u.u = *(const uint4v*)&panB[(wrow * 32 + t * 16 + l15) * LROWU + kc]; at_[t] = u.h;
          u.u = *(const uint4v*)&panB[(wcol * 32 + t * 16 + l15) * LROWU + kc]; bt_[t] = u.h;
        }
#pragma unroll
        for (int ti = 0; ti < 2; ti++)
#pragma unroll
          for (int tj = 0; tj < 2; tj++) {
            aXY[ti][tj] = __builtin_amdgcn_mfma_f32_16x16x32_f16(as_[ti], bt_[tj], aXY[ti][tj], 0, 0, 0);
            aXX[ti][tj] = __builtin_amdgcn_mfma_f32_16x16x32_f16(as_[ti], bs_[tj], aXX[ti][tj], 0, 0, 0);
            aYY[ti][tj] = __builtin_amdgcn_mfma_f32_16x16x32_f16(at_[ti], bt_[tj], aYY[ti][tj], 0, 0, 0);
          }
      }
    }

    if (st + 1 < NSTAGE) {
      CVT_WRITE((st + 1) & 1)          // vmcnt wait lands here, after compute
      __syncthreads();
    }
  }
#undef ISSUE_LOADS
#undef CVT_WRITE

#pragma unroll
  for (int kind = 0; kind < 3; kind++) {
    unsigned short* out = part + ((size_t)(pair * 3 + kind) * KCHUNKS + chunk) * GRAM_N;
#pragma unroll
    for (int ti = 0; ti < 2; ti++)
#pragma unroll
      for (int tj = 0; tj < 2; tj++) {
        const f32x4 v = (kind == 0) ? aXY[ti][tj] : ((kind == 1) ? aXX[ti][tj] : aYY[ti][tj]);
        const int col = wcol * 32 + tj * 16 + l15;
#pragma unroll
        for (int r = 0; r < 4; r++) {
          const int row = wrow * 32 + ti * 16 + quad * 4 + r;
          out[(size_t)row * NB + col] = f2bf_rn(v[r]);
        }
      }
  }
}

// ---------------------------------------------------------------------------
// Kernel 2: reduce bf16 K-chunk partials -> gram[9][128][128] (f32)
// ---------------------------------------------------------------------------
__global__ __launch_bounds__(256) void gram_reduce_kernel(
    const unsigned short* __restrict__ part, float* __restrict__ gram) {
  const int idx = blockIdx.x * 256 + threadIdx.x;   // < 9*16384
  const int g = idx >> 14;
  const int cell = idx & (GRAM_N - 1);
  const unsigned short* p = part + (size_t)g * KCHUNKS * GRAM_N + cell;
  float s = 0.f;
#pragma unroll
  for (int c = 0; c < KCHUNKS; c++) s += bf2f(p[(size_t)c * GRAM_N]);
  gram[idx] = s;
}

// ---------------------------------------------------------------------------
// Kernel 3: Sinkhorn, per (pair, kind) chain. kind0: ft||gt; kind1: faa;
// kind2: gbb. (unchanged — verified twice)
// ---------------------------------------------------------------------------
__global__ __launch_bounds__(256, 1) void sinkhorn_part_kernel(
    const float* __restrict__ gram, float* __restrict__ kdpart) {
  const int pair = blockIdx.x, kind = blockIdx.y;
  const float* Gxy = gram + (size_t)(3 * pair + 0) * GRAM_N;
  const float* Gxx = gram + (size_t)(3 * pair + 1) * GRAM_N;
  const float* Gyy = gram + (size_t)(3 * pair + 2) * GRAM_N;

  __shared__ float CL[NB * CPAD];     // 67584 B, f32 cost matrix
  __shared__ f32x4 h4a[NB / 4];       // pot0 (f-side)
  __shared__ f32x4 h4b[NB / 4];       // pot1 (g-side, kind0 only)
  __shared__ float nx[NB], ny[NB];
  __shared__ float red[256];

  const int tid = threadIdx.x;
  if (tid < NB) {
    nx[tid] = Gxx[tid * (NB + 1)];
    ny[tid] = Gyy[tid * (NB + 1)];
    ((float*)h4a)[tid] = 0.f;
    ((float*)h4b)[tid] = 0.f;
  }
  __syncthreads();

  const float* G  = (kind == 0) ? Gxy : ((kind == 1) ? Gxx : Gyy);
  const float* rn = (kind == 2) ? ny : nx;
  const float* cn = (kind == 1) ? nx : ny;
  for (int idx = tid; idx < GRAM_N; idx += 256) {
    const int i = idx >> 7, j = idx & 127;
    CL[i * CPAD + j] = 2.0f * fmaxf(rn[i] + cn[j] - 2.0f * G[idx], 0.0f);
  }
  __syncthreads();

  const float rho = 250000.0f;
  const float AL = -4.852030263919617f;     // -log(128)
  const float LOG2E = 1.4426950408889634f;
  const float LN2 = 0.6931471805599453f;
  const int grp = tid >> 7;
  const int i = tid & 127;
  const bool active = (kind == 0) || (grp == 0);
  const bool colread = (kind == 0) && (grp == 1);

  // register-cache this thread's C row (or column for gt)
  f32x4 crow[32];
  if (active) {
    if (colread) {
#pragma unroll
      for (int jj = 0; jj < 32; jj++) {
        f32x4 v;
        v[0] = CL[(4 * jj + 0) * CPAD + i];
        v[1] = CL[(4 * jj + 1) * CPAD + i];
        v[2] = CL[(4 * jj + 2) * CPAD + i];
        v[3] = CL[(4 * jj + 3) * CPAD + i];
        crow[jj] = v;
      }
    } else {
#pragma unroll
      for (int jj = 0; jj < 32; jj++)
        crow[jj] = *(const f32x4*)&CL[i * CPAD + 4 * jj];
    }
  }

  float eps = 1.0f;
  for (int it = 0; it < 9; it++) {
    if (it == 8) eps = 2.5e-5f;             // BLUR^P
    const float inv_eps = 1.0f / eps;
    const float damp = 1.0f / (1.0f + eps / rho);
    const float ebl = eps * AL;

    float newp = 0.f;
    if (active) {
      const f32x4* h = (kind == 0 && grp == 0) ? h4b : h4a;
      // pass 1: m = max_j (h[j] - C[j])
      f32x4 m4 = (f32x4){-3.0e38f, -3.0e38f, -3.0e38f, -3.0e38f};
#pragma unroll
      for (int jj = 0; jj < 32; jj++) {
        const f32x4 u = h[jj] - crow[jj];
        m4[0] = fmaxf(m4[0], u[0]); m4[1] = fmaxf(m4[1], u[1]);
        m4[2] = fmaxf(m4[2], u[2]); m4[3] = fmaxf(m4[3], u[3]);
      }
      const float m = fmaxf(fmaxf(m4[0], m4[1]), fmaxf(m4[2], m4[3]));
      // pass 2: S = sum_j exp2((u - m) * k); subtract-first keeps arg <= 0
      const float k = inv_eps * LOG2E;
      f32x4 s4 = (f32x4){0.f, 0.f, 0.f, 0.f};
#pragma unroll
      for (int jj = 0; jj < 32; jj++) {
        const f32x4 u = h[jj] - crow[jj];
        s4[0] += __builtin_exp2f((u[0] - m) * k);
        s4[1] += __builtin_exp2f((u[1] - m) * k);
        s4[2] += __builtin_exp2f((u[2] - m) * k);
        s4[3] += __builtin_exp2f((u[3] - m) * k);
      }
      const float Ssum = (s4[0] + s4[1]) + (s4[2] + s4[3]);   // >= 1
      // softmin = -(m + ebl + eps*ln(S))
      const float sm = -(m + ebl + eps * (LN2 * __log2f(Ssum)));
      if (kind == 0) newp = damp * sm;
      else           newp = 0.5f * (((const float*)h4a)[i] + damp * sm);
    }
    __syncthreads();                        // all reads of h done
    if (active) {
      if (grp == 0) ((float*)h4a)[i] = newp;
      else          ((float*)h4b)[i] = newp;
    }
    __syncthreads();                        // new pots visible
    eps *= 0.25f;                           // SCALING^P
  }

  float v = 0.f;
  if (kind == 0) {
    v = (grp == 0) ? -__expf(-((const float*)h4a)[i] / rho)
                   : -__expf(-((const float*)h4b)[i] / rho);
  } else if (grp == 0) {
    v = __expf(-((const float*)h4a)[i] / rho);
  }
  red[tid] = v;
  __syncthreads();
  for (int st = 128; st > 0; st >>= 1) {
    if (tid < st) red[tid] += red[tid + st];
    __syncthreads();
  }
  if (tid == 0) kdpart[pair * 3 + kind] = red[0];
}

// ---------------------------------------------------------------------------
// Kernel 4: one-hot structure of delta -> gathers. block per (b,s).
// ---------------------------------------------------------------------------
__global__ __launch_bounds__(256) void ps_kernel(
    const float* __restrict__ lc, const float* __restrict__ lt, const float* __restrict__ le,
    const float* __restrict__ batch,
    float* __restrict__ pc, float* __restrict__ pt, float* __restrict__ pe,
    float* __restrict__ aarr) {
  const int bs = blockIdx.x;
  const int b = bs / S_DIM, s = bs % S_DIM;
  const float* brow = batch + ((size_t)b * T_DIM + (s + 1)) * (2 * Q_DIM);
  __shared__ int sq;
  __shared__ float sds;
  if (threadIdx.x == 0) sq = 0;
  __syncthreads();
  for (int q = threadIdx.x; q < Q_DIM; q += 256) {
    float d0 = brow[q], d1 = brow[Q_DIM + q];
    if (d0 + d1 > 0.5f) { sq = q; sds = d0 - d1; }   // exactly one thread fires
  }
  __syncthreads();
  if (threadIdx.x == 0) {
    const size_t off = ((size_t)b * T_DIM + s) * Q_DIM + sq;
    pc[bs] = 2.0f * lc[off];   // 1/TEMP
    pt[bs] = 2.0f * lt[off];
    pe[bs] = 2.0f * le[off];
    aarr[bs] = (sds > 0.0f) ? 1.0f : 0.0f;
  }
}

// ---------------------------------------------------------------------------
// Kernel 5: embed loss: sum of squared diffs. 1600 blocks = 1 tile/thread
// (was 512: only 8 waves/CU in flight, marginal for latency hiding).
// ---------------------------------------------------------------------------
__global__ __launch_bounds__(256) void embed_kernel(
    const f32x4* __restrict__ hs, const f32x4* __restrict__ ht,
    const f32x4* __restrict__ ds, const f32x4* __restrict__ dt,
    float* __restrict__ acc) {
  const int N4 = NB * T_DIM * H_DIM / 4;   // 409600
  float sum = 0.f;
  for (int idx = blockIdx.x * 256 + threadIdx.x; idx < N4; idx += gridDim.x * 256) {
    f32x4 a = hs[idx] - ht[idx];
    f32x4 b = ds[idx] - dt[idx];
    sum += a[0]*a[0] + a[1]*a[1] + a[2]*a[2] + a[3]*a[3]
         + b[0]*b[0] + b[1]*b[1] + b[2]*b[2] + b[3]*b[3];
  }
  for (int off = 32; off > 0; off >>= 1) sum += __shfl_down(sum, off, 64);
  __shared__ float wsum[4];
  const int lane = threadIdx.x & 63, wv = threadIdx.x >> 6;
  if (lane == 0) wsum[wv] = sum;
  __syncthreads();
  if (threadIdx.x == 0) atomicAdd(acc, wsum[0] + wsum[1] + wsum[2] + wsum[3]);
}

// ---------------------------------------------------------------------------
// Kernel 6: masked CE + final combine. 1 block, 128 threads.
// Round-3: stage all four 128x49 arrays into LDS (coalesced, once) instead
// of 3x49 serial GLOBAL loads per thread per pass — the old form was a
// ~200cy-per-load dependent chain on a single block. Stride 49 (odd) is
// bank-conflict-free for the per-thread row walk.
// ---------------------------------------------------------------------------
__global__ __launch_bounds__(128) void ce_final_kernel(
    const float* __restrict__ pc, const float* __restrict__ pt, const float* __restrict__ pe,
    const float* __restrict__ aarr, const float* __restrict__ kdpart,
    const float* __restrict__ emb, float* __restrict__ out) {
  __shared__ float sx[4][NB][S_DIM];   // 0:pt 1:pc 2:pe 3:a — 100352 B
  const int tid = threadIdx.x;
  for (int idx = tid; idx < NB * S_DIM; idx += 128) {
    const int b = idx / S_DIM, s = idx - b * S_DIM;
    sx[0][b][s] = pt[idx];
    sx[1][b][s] = pc[idx];
    sx[2][b][s] = pe[idx];
    sx[3][b][s] = aarr[idx];
  }
  __syncthreads();

  const int b = tid;
  int last = -1;
  for (int s = 0; s < S_DIM; s++)
    if (sx[1][b][s] > 0.0f) last = s;
  const int L = (last >= 0) ? (last + 1) : S_DIM;

  float loss = 0.f;
#pragma unroll
  for (int k = 0; k < 3; k++) {
    float m = -3.0e38f;
    for (int s = 0; s < L; s++) m = fmaxf(m, sx[k][b][s]);
    float sum = 0.f;
    for (int s = 0; s < L; s++) sum += __expf(sx[k][b][s] - m);
    const float lse = m + __logf(sum);
    float l = 0.f;
    for (int s = 0; s < L; s++) l += sx[3][b][s] * (sx[k][b][s] - lse);
    loss -= l;
  }

  __shared__ float red[128];
  red[b] = loss;
  __syncthreads();
  for (int st = 64; st > 0; st >>= 1) {
    if (b < st) red[b] += red[b + st];
    __syncthreads();
  }
  if (b == 0) {
    float kd = 0.f;
    for (int k = 0; k < 9; k++) kd += kdpart[k];
    // w * a_w = (rho + eps_final/2) / 128 ; DIST_W = 0.01
    out[0] = red[0] + 0.01f * (250000.0000125f / 128.0f) * kd + 0.5f * emb[0];
  }
}

// ---------------------------------------------------------------------------
extern "C" void kernel_launch(void* const* d_in, const int* in_sizes, int n_in,
                              void* d_out, int out_size, void* d_ws, size_t ws_size,
                              hipStream_t stream) {
  const float* lc    = (const float*)d_in[0];
  const float* lt    = (const float*)d_in[1];
  const float* le    = (const float*)d_in[2];
  const float* ltc   = (const float*)d_in[3];
  const float* ltt   = (const float*)d_in[4];
  const float* lte   = (const float*)d_in[5];
  const float* ohs   = (const float*)d_in[6];
  const float* oht   = (const float*)d_in[7];
  const float* ods   = (const float*)d_in[8];
  const float* odt   = (const float*)d_in[9];
  const float* batch = (const float*)d_in[10];

  unsigned short* part = (unsigned short*)d_ws;        // 9*80*16384*2B = 23.6 MB
  float* gram = (float*)(part + (size_t)9 * KCHUNKS * GRAM_N);  // 9*16384 f32
  float* pcb  = gram + 9 * GRAM_N;                     // 128*49 each
  float* ptb  = pcb + NB * S_DIM;
  float* peb  = ptb + NB * S_DIM;
  float* ab   = peb + NB * S_DIM;
  float* kdp  = ab + NB * S_DIM;                       // 9
  float* emb  = kdp + 9;                               // 1

  hipMemsetAsync(emb, 0, sizeof(float), stream);

  embed_kernel<<<1600, 256, 0, stream>>>(
      (const f32x4*)ohs, (const f32x4*)oht, (const f32x4*)ods, (const f32x4*)odt, emb);

  ps_kernel<<<NB * S_DIM, 256, 0, stream>>>(lc, lt, le, batch, pcb, ptb, peb, ab);

  gram_fused_kernel<<<dim3(KCHUNKS, 3), 1024, 0, stream>>>(lc, lt, le, ltc, ltt, lte, part);

  gram_reduce_kernel<<<(9 * GRAM_N) / 256, 256, 0, stream>>>(part, gram);

  sinkhorn_part_kernel<<<dim3(3, 3), 256, 0, stream>>>(gram, kdp);

  ce_final_kernel<<<1, 128, 0, stream>>>(pcb, ptb, peb, ab, kdp, emb, (float*)d_out);
}

// Round 4
// 342.882 us; speedup vs baseline: 1.4761x; 1.0040x over previous
//
#include <hip/hip_runtime.h>

#define NB 128
#define T_DIM 50
#define Q_DIM 1024
#define H_DIM 256
#define S_DIM 49                 // MAX_STEP - 1
#define K_DIM 51200              // T*Q
#define KCHUNKS 80
#define KC 640                   // K per block
#define BK 64                    // K per LDS stage
#define NSTAGE 10                // KC/BK
#define GRAM_N (NB * NB)         // 16384
#define LROWU 36                 // uints per padded LDS row (64 f16 + 8 pad)
#define CPAD 132                 // padded f32 row for sinkhorn cost matrix

typedef __attribute__((ext_vector_type(4))) float f32x4;
typedef __attribute__((ext_vector_type(8))) _Float16 half8v;
typedef __attribute__((ext_vector_type(4))) unsigned int uint4v;
typedef __attribute__((ext_vector_type(2))) unsigned int uint2v;
using pk2_t = decltype(__builtin_amdgcn_cvt_pkrtz(0.0f, 0.0f));

union PKU { pk2_t p; unsigned int u; };
union U4H8 { uint4v u; half8v h; };

__device__ inline unsigned short f2bf_rn(float x) {   // round-nearest-even bf16
  union { float f; unsigned int u; } v; v.f = x;
  unsigned int r = v.u + 0x7FFFu + ((v.u >> 16) & 1u);
  return (unsigned short)(r >> 16);
}
__device__ inline float bf2f(unsigned short b) {
  union { float f; unsigned int u; } v; v.u = ((unsigned int)b) << 16;
  return v.f;
}

// ---------------------------------------------------------------------------
// gram_fused helpers
// ---------------------------------------------------------------------------
__device__ __forceinline__ void issue_loads(
    const float* __restrict__ S, const float* __restrict__ Tm,
    size_t ro0, size_t ro1, int kpos, int kq,
    f32x4& p0, f32x4& p1, f32x4& p2, f32x4& p3) {
  const float* pS = S + kpos + kq * 4;
  const float* pT = Tm + kpos + kq * 4;
  p0 = *(const f32x4*)(pS + ro0);
  p1 = *(const f32x4*)(pS + ro1);
  p2 = *(const f32x4*)(pT + ro0);
  p3 = *(const f32x4*)(pT + ro1);
}

__device__ __forceinline__ void cvt_write(
    unsigned int* __restrict__ panA, unsigned int* __restrict__ panB,
    int r0, int kq,
    const f32x4& p0, const f32x4& p1, const f32x4& p2, const f32x4& p3) {
  PKU a, b; uint2v w;
  a.p = __builtin_amdgcn_cvt_pkrtz(p0[0], p0[1]);
  b.p = __builtin_amdgcn_cvt_pkrtz(p0[2], p0[3]);
  w.x = a.u; w.y = b.u;
  *(uint2v*)&panA[r0 * LROWU + kq * 2] = w;
  a.p = __builtin_amdgcn_cvt_pkrtz(p1[0], p1[1]);
  b.p = __builtin_amdgcn_cvt_pkrtz(p1[2], p1[3]);
  w.x = a.u; w.y = b.u;
  *(uint2v*)&panA[(r0 + 64) * LROWU + kq * 2] = w;
  a.p = __builtin_amdgcn_cvt_pkrtz(p2[0], p2[1]);
  b.p = __builtin_amdgcn_cvt_pkrtz(p2[2], p2[3]);
  w.x = a.u; w.y = b.u;
  *(uint2v*)&panB[r0 * LROWU + kq * 2] = w;
  a.p = __builtin_amdgcn_cvt_pkrtz(p3[0], p3[1]);
  b.p = __builtin_amdgcn_cvt_pkrtz(p3[2], p3[3]);
  w.x = a.u; w.y = b.u;
  *(uint2v*)&panB[(r0 + 64) * LROWU + kq * 2] = w;
}

__device__ __forceinline__ void compute_stage(
    const unsigned int* __restrict__ panA, const unsigned int* __restrict__ panB,
    int wrow, int wcol, int l15, int quad,
    f32x4 (&aXY)[2][2], f32x4 (&aXX)[2][2], f32x4 (&aYY)[2][2]) {
#pragma unroll
  for (int ks = 0; ks < 2; ks++) {
    const int kc = ks * 16 + quad * 4;
    half8v as_[2], bs_[2], at_[2], bt_[2];
#pragma unroll
    for (int t = 0; t < 2; t++) {
      U4H8 u;
      u.u = *(const uint4v*)&panA[(wrow * 32 + t * 16 + l15) * LROWU + kc]; as_[t] = u.h;
      u.u = *(const uint4v*)&panA[(wcol * 32 + t * 16 + l15) * LROWU + kc]; bs_[t] = u.h;
      u.u = *(const uint4v*)&panB[(wrow * 32 + t * 16 + l15) * LROWU + kc]; at_[t] = u.h;
      u.u = *(const uint4v*)&panB[(wcol * 32 + t * 16 + l15) * LROWU + kc]; bt_[t] = u.h;
    }
#pragma unroll
    for (int ti = 0; ti < 2; ti++)
#pragma unroll
      for (int tj = 0; tj < 2; tj++) {
        aXY[ti][tj] = __builtin_amdgcn_mfma_f32_16x16x32_f16(as_[ti], bt_[tj], aXY[ti][tj], 0, 0, 0);
        aXX[ti][tj] = __builtin_amdgcn_mfma_f32_16x16x32_f16(as_[ti], bs_[tj], aXX[ti][tj], 0, 0, 0);
        aYY[ti][tj] = __builtin_amdgcn_mfma_f32_16x16x32_f16(at_[ti], bt_[tj], aYY[ti][tj], 0, 0, 0);
      }
  }
}

// ---------------------------------------------------------------------------
// Kernel 1: FUSED per-pair grams (XY, XX, YY) via 16x16x32 f16 MFMA.
// grid = (KCHUNKS, 3), block = 1024 (16 waves), 1 block/CU (LDS 73728).
//
// Round-4: 2-DEEP register prefetch (sets A=even stages, B=odd stages) +
// double-buffered LDS + one barrier per stage. Loads for stage s are issued
// a FULL iteration before their vmcnt wait (window ~2 stage periods >
// ~6k cy HBM delivery of 64KB/CU). The compiler's per-register vmcnt gives
// s_waitcnt vmcnt(4) at each cvt_write — the newer prefetch set stays in
// flight across the barrier (counted-vmcnt pattern, no inline asm).
//
// Schedule (NSTAGE even):
//   prologue: issue(0)->A; issue(1)->B; write A->L0; barrier
//   iter s2 (even stage): [issue(s2+2)->A] compute L0; write B->L1; barrier
//        (odd stage)    : [issue(s2+3)->B] compute L1; [write A->L0; barrier]
// Hazards: write to L0 at iter end follows the mid-iter barrier, after all
// waves' compute(L0); write to L1 mid-iter follows the end-of-prev-iter
// barrier, after all waves' compute(L1). pre-set WAR is program-order within
// a thread (issue overwrites a set only after its cvt_write consumed it).
// Numerics identical to round 0 (same RTZ cvt, MFMA, chunking, bf16 parts).
// VGPR ~96 expected (<128 keeps 4 waves/SIMD). Spill tripwire: WRITE_SIZE.
// ---------------------------------------------------------------------------
__global__ __launch_bounds__(1024) void gram_fused_kernel(
    const float* __restrict__ s0, const float* __restrict__ s1, const float* __restrict__ s2,
    const float* __restrict__ t0, const float* __restrict__ t1, const float* __restrict__ t2,
    unsigned short* __restrict__ part) {
  __shared__ unsigned int pan[2][2][NB * LROWU];   // [buf][A/B], 73728 B

  const int chunk = blockIdx.x;
  const int pair = blockIdx.y;
  const float* S  = (pair == 0) ? s0 : ((pair == 1) ? s1 : s2);
  const float* Tm = (pair == 0) ? t0 : ((pair == 1) ? t1 : t2);

  const int tid = threadIdx.x;
  const int wave = tid >> 6, lane = tid & 63;
  const int wrow = wave >> 2, wcol = wave & 3;
  const int l15 = lane & 15, quad = lane >> 4;

  f32x4 aXY[2][2], aXX[2][2], aYY[2][2];
#pragma unroll
  for (int i = 0; i < 2; i++)
#pragma unroll
    for (int j = 0; j < 2; j++) {
      aXY[i][j] = (f32x4){0.f, 0.f, 0.f, 0.f};
      aXX[i][j] = (f32x4){0.f, 0.f, 0.f, 0.f};
      aYY[i][j] = (f32x4){0.f, 0.f, 0.f, 0.f};
    }

  const int r0 = tid >> 4;              // 0..63 (i=0); i=1 -> r0+64
  const int kq = tid & 15;
  const size_t ro0 = (size_t)r0 * K_DIM;
  const size_t ro1 = (size_t)(r0 + 64) * K_DIM;
  const int kbase = chunk * KC;

  f32x4 A0, A1, A2, A3;   // even-stage prefetch set
  f32x4 B0, B1, B2, B3;   // odd-stage prefetch set

  issue_loads(S, Tm, ro0, ro1, kbase, kq, A0, A1, A2, A3);
  issue_loads(S, Tm, ro0, ro1, kbase + BK, kq, B0, B1, B2, B3);
  cvt_write(&pan[0][0][0], &pan[0][1][0], r0, kq, A0, A1, A2, A3);
  __syncthreads();

  for (int s2 = 0; s2 < NSTAGE; s2 += 2) {
    // even stage s2: compute L0
    if (s2 + 2 < NSTAGE)
      issue_loads(S, Tm, ro0, ro1, kbase + (s2 + 2) * BK, kq, A0, A1, A2, A3);
    compute_stage(&pan[0][0][0], &pan[0][1][0], wrow, wcol, l15, quad, aXY, aXX, aYY);
    cvt_write(&pan[1][0][0], &pan[1][1][0], r0, kq, B0, B1, B2, B3);  // vmcnt(4)
    __syncthreads();

    // odd stage s2+1: compute L1
    if (s2 + 3 < NSTAGE)
      issue_loads(S, Tm, ro0, ro1, kbase + (s2 + 3) * BK, kq, B0, B1, B2, B3);
    compute_stage(&pan[1][0][0], &pan[1][1][0], wrow, wcol, l15, quad, aXY, aXX, aYY);
    if (s2 + 2 < NSTAGE) {
      cvt_write(&pan[0][0][0], &pan[0][1][0], r0, kq, A0, A1, A2, A3);  // vmcnt(4)
      __syncthreads();
    }
  }

#pragma unroll
  for (int kind = 0; kind < 3; kind++) {
    unsigned short* out = part + ((size_t)(pair * 3 + kind) * KCHUNKS + chunk) * GRAM_N;
#pragma unroll
    for (int ti = 0; ti < 2; ti++)
#pragma unroll
      for (int tj = 0; tj < 2; tj++) {
        const f32x4 v = (kind == 0) ? aXY[ti][tj] : ((kind == 1) ? aXX[ti][tj] : aYY[ti][tj]);
        const int col = wcol * 32 + tj * 16 + l15;
#pragma unroll
        for (int r = 0; r < 4; r++) {
          const int row = wrow * 32 + ti * 16 + quad * 4 + r;
          out[(size_t)row * NB + col] = f2bf_rn(v[r]);
        }
      }
  }
}

// ---------------------------------------------------------------------------
// Kernel 2: reduce bf16 K-chunk partials -> gram[9][128][128] (f32)
// ---------------------------------------------------------------------------
__global__ __launch_bounds__(256) void gram_reduce_kernel(
    const unsigned short* __restrict__ part, float* __restrict__ gram) {
  const int idx = blockIdx.x * 256 + threadIdx.x;   // < 9*16384
  const int g = idx >> 14;
  const int cell = idx & (GRAM_N - 1);
  const unsigned short* p = part + (size_t)g * KCHUNKS * GRAM_N + cell;
  float s = 0.f;
#pragma unroll
  for (int c = 0; c < KCHUNKS; c++) s += bf2f(p[(size_t)c * GRAM_N]);
  gram[idx] = s;
}

// ---------------------------------------------------------------------------
// Kernel 3: Sinkhorn, per (pair, kind) chain. (unchanged — verified 3x)
// ---------------------------------------------------------------------------
__global__ __launch_bounds__(256, 1) void sinkhorn_part_kernel(
    const float* __restrict__ gram, float* __restrict__ kdpart) {
  const int pair = blockIdx.x, kind = blockIdx.y;
  const float* Gxy = gram + (size_t)(3 * pair + 0) * GRAM_N;
  const float* Gxx = gram + (size_t)(3 * pair + 1) * GRAM_N;
  const float* Gyy = gram + (size_t)(3 * pair + 2) * GRAM_N;

  __shared__ float CL[NB * CPAD];     // 67584 B, f32 cost matrix
  __shared__ f32x4 h4a[NB / 4];       // pot0 (f-side)
  __shared__ f32x4 h4b[NB / 4];       // pot1 (g-side, kind0 only)
  __shared__ float nx[NB], ny[NB];
  __shared__ float red[256];

  const int tid = threadIdx.x;
  if (tid < NB) {
    nx[tid] = Gxx[tid * (NB + 1)];
    ny[tid] = Gyy[tid * (NB + 1)];
    ((float*)h4a)[tid] = 0.f;
    ((float*)h4b)[tid] = 0.f;
  }
  __syncthreads();

  const float* G  = (kind == 0) ? Gxy : ((kind == 1) ? Gxx : Gyy);
  const float* rn = (kind == 2) ? ny : nx;
  const float* cn = (kind == 1) ? nx : ny;
  for (int idx = tid; idx < GRAM_N; idx += 256) {
    const int i = idx >> 7, j = idx & 127;
    CL[i * CPAD + j] = 2.0f * fmaxf(rn[i] + cn[j] - 2.0f * G[idx], 0.0f);
  }
  __syncthreads();

  const float rho = 250000.0f;
  const float AL = -4.852030263919617f;     // -log(128)
  const float LOG2E = 1.4426950408889634f;
  const float LN2 = 0.6931471805599453f;
  const int grp = tid >> 7;
  const int i = tid & 127;
  const bool active = (kind == 0) || (grp == 0);
  const bool colread = (kind == 0) && (grp == 1);

  // register-cache this thread's C row (or column for gt)
  f32x4 crow[32];
  if (active) {
    if (colread) {
#pragma unroll
      for (int jj = 0; jj < 32; jj++) {
        f32x4 v;
        v[0] = CL[(4 * jj + 0) * CPAD + i];
        v[1] = CL[(4 * jj + 1) * CPAD + i];
        v[2] = CL[(4 * jj + 2) * CPAD + i];
        v[3] = CL[(4 * jj + 3) * CPAD + i];
        crow[jj] = v;
      }
    } else {
#pragma unroll
      for (int jj = 0; jj < 32; jj++)
        crow[jj] = *(const f32x4*)&CL[i * CPAD + 4 * jj];
    }
  }

  float eps = 1.0f;
  for (int it = 0; it < 9; it++) {
    if (it == 8) eps = 2.5e-5f;             // BLUR^P
    const float inv_eps = 1.0f / eps;
    const float damp = 1.0f / (1.0f + eps / rho);
    const float ebl = eps * AL;

    float newp = 0.f;
    if (active) {
      const f32x4* h = (kind == 0 && grp == 0) ? h4b : h4a;
      // pass 1: m = max_j (h[j] - C[j])
      f32x4 m4 = (f32x4){-3.0e38f, -3.0e38f, -3.0e38f, -3.0e38f};
#pragma unroll
      for (int jj = 0; jj < 32; jj++) {
        const f32x4 u = h[jj] - crow[jj];
        m4[0] = fmaxf(m4[0], u[0]); m4[1] = fmaxf(m4[1], u[1]);
        m4[2] = fmaxf(m4[2], u[2]); m4[3] = fmaxf(m4[3], u[3]);
      }
      const float m = fmaxf(fmaxf(m4[0], m4[1]), fmaxf(m4[2], m4[3]));
      // pass 2: S = sum_j exp2((u - m) * k); subtract-first keeps arg <= 0
      const float k = inv_eps * LOG2E;
      f32x4 s4 = (f32x4){0.f, 0.f, 0.f, 0.f};
#pragma unroll
      for (int jj = 0; jj < 32; jj++) {
        const f32x4 u = h[jj] - crow[jj];
        s4[0] += __builtin_exp2f((u[0] - m) * k);
        s4[1] += __builtin_exp2f((u[1] - m) * k);
        s4[2] += __builtin_exp2f((u[2] - m) * k);
        s4[3] += __builtin_exp2f((u[3] - m) * k);
      }
      const float Ssum = (s4[0] + s4[1]) + (s4[2] + s4[3]);   // >= 1
      // softmin = -(m + ebl + eps*ln(S))
      const float sm = -(m + ebl + eps * (LN2 * __log2f(Ssum)));
      if (kind == 0) newp = damp * sm;
      else           newp = 0.5f * (((const float*)h4a)[i] + damp * sm);
    }
    __syncthreads();                        // all reads of h done
    if (active) {
      if (grp == 0) ((float*)h4a)[i] = newp;
      else          ((float*)h4b)[i] = newp;
    }
    __syncthreads();                        // new pots visible
    eps *= 0.25f;                           // SCALING^P
  }

  float v = 0.f;
  if (kind == 0) {
    v = (grp == 0) ? -__expf(-((const float*)h4a)[i] / rho)
                   : -__expf(-((const float*)h4b)[i] / rho);
  } else if (grp == 0) {
    v = __expf(-((const float*)h4a)[i] / rho);
  }
  red[tid] = v;
  __syncthreads();
  for (int st = 128; st > 0; st >>= 1) {
    if (tid < st) red[tid] += red[tid + st];
    __syncthreads();
  }
  if (tid == 0) kdpart[pair * 3 + kind] = red[0];
}

// ---------------------------------------------------------------------------
// Kernel 4: one-hot gather. Round-4: ONE WAVE per (b,s) — ballot+shfl, no
// LDS, no barriers (was: one 256-thread block with 2 __syncthreads each;
// 6272 tiny blocks of launch+barrier overhead).
// ---------------------------------------------------------------------------
__global__ __launch_bounds__(256) void ps_kernel(
    const float* __restrict__ lc, const float* __restrict__ lt, const float* __restrict__ le,
    const float* __restrict__ batch,
    float* __restrict__ pc, float* __restrict__ pt, float* __restrict__ pe,
    float* __restrict__ aarr) {
  const int w = blockIdx.x * 4 + (threadIdx.x >> 6);   // wave id = b*S_DIM+s
  if (w >= NB * S_DIM) return;
  const int lane = threadIdx.x & 63;
  const int b = w / S_DIM, s = w - b * S_DIM;
  const float* brow = batch + ((size_t)b * T_DIM + (s + 1)) * (2 * Q_DIM);

  int qv = 0; float dsv = 0.f; bool found = false;
#pragma unroll
  for (int c = 0; c < 4; c++) {
    const int base = c * 256 + lane * 4;             // coalesced f32x4
    const f32x4 d0 = *(const f32x4*)(brow + base);
    const f32x4 d1 = *(const f32x4*)(brow + Q_DIM + base);
#pragma unroll
    for (int j = 0; j < 4; j++)
      if (d0[j] + d1[j] > 0.5f) { qv = base + j; dsv = d0[j] - d1[j]; found = true; }
  }
  const unsigned long long m = __ballot(found);
  const int src = (m != 0ull) ? (__ffsll((unsigned long long)m) - 1) : 0;
  qv = __shfl(qv, src, 64);
  dsv = __shfl(dsv, src, 64);
  if (lane == 0) {
    const size_t off = ((size_t)b * T_DIM + s) * Q_DIM + qv;
    pc[w] = 2.0f * lc[off];   // 1/TEMP
    pt[w] = 2.0f * lt[off];
    pe[w] = 2.0f * le[off];
    aarr[w] = (m != 0ull && dsv > 0.0f) ? 1.0f : 0.0f;
  }
}

// ---------------------------------------------------------------------------
// Kernel 5: embed loss: sum of squared diffs. 1600 blocks = 1 tile/thread.
// ---------------------------------------------------------------------------
__global__ __launch_bounds__(256) void embed_kernel(
    const f32x4* __restrict__ hs, const f32x4* __restrict__ ht,
    const f32x4* __restrict__ ds, const f32x4* __restrict__ dt,
    float* __restrict__ acc) {
  const int N4 = NB * T_DIM * H_DIM / 4;   // 409600
  float sum = 0.f;
  for (int idx = blockIdx.x * 256 + threadIdx.x; idx < N4; idx += gridDim.x * 256) {
    f32x4 a = hs[idx] - ht[idx];
    f32x4 b = ds[idx] - dt[idx];
    sum += a[0]*a[0] + a[1]*a[1] + a[2]*a[2] + a[3]*a[3]
         + b[0]*b[0] + b[1]*b[1] + b[2]*b[2] + b[3]*b[3];
  }
  for (int off = 32; off > 0; off >>= 1) sum += __shfl_down(sum, off, 64);
  __shared__ float wsum[4];
  const int lane = threadIdx.x & 63, wv = threadIdx.x >> 6;
  if (lane == 0) wsum[wv] = sum;
  __syncthreads();
  if (threadIdx.x == 0) atomicAdd(acc, wsum[0] + wsum[1] + wsum[2] + wsum[3]);
}

// ---------------------------------------------------------------------------
// Kernel 6: masked CE + final combine. 1 block, 128 threads. LDS-staged.
// ---------------------------------------------------------------------------
__global__ __launch_bounds__(128) void ce_final_kernel(
    const float* __restrict__ pc, const float* __restrict__ pt, const float* __restrict__ pe,
    const float* __restrict__ aarr, const float* __restrict__ kdpart,
    const float* __restrict__ emb, float* __restrict__ out) {
  __shared__ float sx[4][NB][S_DIM];   // 0:pt 1:pc 2:pe 3:a — 100352 B
  const int tid = threadIdx.x;
  for (int idx = tid; idx < NB * S_DIM; idx += 128) {
    const int b = idx / S_DIM, s = idx - b * S_DIM;
    sx[0][b][s] = pt[idx];
    sx[1][b][s] = pc[idx];
    sx[2][b][s] = pe[idx];
    sx[3][b][s] = aarr[idx];
  }
  __syncthreads();

  const int b = tid;
  int last = -1;
  for (int s = 0; s < S_DIM; s++)
    if (sx[1][b][s] > 0.0f) last = s;
  const int L = (last >= 0) ? (last + 1) : S_DIM;

  float loss = 0.f;
#pragma unroll
  for (int k = 0; k < 3; k++) {
    float m = -3.0e38f;
    for (int s = 0; s < L; s++) m = fmaxf(m, sx[k][b][s]);
    float sum = 0.f;
    for (int s = 0; s < L; s++) sum += __expf(sx[k][b][s] - m);
    const float lse = m + __logf(sum);
    float l = 0.f;
    for (int s = 0; s < L; s++) l += sx[3][b][s] * (sx[k][b][s] - lse);
    loss -= l;
  }

  __shared__ float red[128];
  red[b] = loss;
  __syncthreads();
  for (int st = 64; st > 0; st >>= 1) {
    if (b < st) red[b] += red[b + st];
    __syncthreads();
  }
  if (b == 0) {
    float kd = 0.f;
    for (int k = 0; k < 9; k++) kd += kdpart[k];
    // w * a_w = (rho + eps_final/2) / 128 ; DIST_W = 0.01
    out[0] = red[0] + 0.01f * (250000.0000125f / 128.0f) * kd + 0.5f * emb[0];
  }
}

// ---------------------------------------------------------------------------
extern "C" void kernel_launch(void* const* d_in, const int* in_sizes, int n_in,
                              void* d_out, int out_size, void* d_ws, size_t ws_size,
                              hipStream_t stream) {
  const float* lc    = (const float*)d_in[0];
  const float* lt    = (const float*)d_in[1];
  const float* le    = (const float*)d_in[2];
  const float* ltc   = (const float*)d_in[3];
  const float* ltt   = (const float*)d_in[4];
  const float* lte   = (const float*)d_in[5];
  const float* ohs   = (const float*)d_in[6];
  const float* oht   = (const float*)d_in[7];
  const float* ods   = (const float*)d_in[8];
  const float* odt   = (const float*)d_in[9];
  const float* batch = (const float*)d_in[10];

  unsigned short* part = (unsigned short*)d_ws;        // 9*80*16384*2B = 23.6 MB
  float* gram = (float*)(part + (size_t)9 * KCHUNKS * GRAM_N);  // 9*16384 f32
  float* pcb  = gram + 9 * GRAM_N;                     // 128*49 each
  float* ptb  = pcb + NB * S_DIM;
  float* peb  = ptb + NB * S_DIM;
  float* ab   = peb + NB * S_DIM;
  float* kdp  = ab + NB * S_DIM;                       // 9
  float* emb  = kdp + 9;                               // 1

  hipMemsetAsync(emb, 0, sizeof(float), stream);

  embed_kernel<<<1600, 256, 0, stream>>>(
      (const f32x4*)ohs, (const f32x4*)oht, (const f32x4*)ods, (const f32x4*)odt, emb);

  ps_kernel<<<(NB * S_DIM + 3) / 4, 256, 0, stream>>>(lc, lt, le, batch, pcb, ptb, peb, ab);

  gram_fused_kernel<<<dim3(KCHUNKS, 3), 1024, 0, stream>>>(lc, lt, le, ltc, ltt, lte, part);

  gram_reduce_kernel<<<(9 * GRAM_N) / 256, 256, 0, stream>>>(part, gram);

  sinkhorn_part_kernel<<<dim3(3, 3), 256, 0, stream>>>(gram, kdp);

  ce_final_kernel<<<1, 128, 0, stream>>>(pcb, ptb, peb, ab, kdp, emb, (float*)d_out);
}